// Round 3
// baseline (107.684 us; speedup 1.0000x reference)
//
#include <hip/hip_runtime.h>
#include <stdint.h>

// Log-sparse causal attention, B=4 L=2048 H=8 E=D=64, fp32 in/out.
// Allowed distances delta = q - j: window {0..5} U {6,7,9,13,21,37,69,133,261,517,1029}
// -> exactly 17 candidate keys per query; direct sparse gather, no score matrix.
//
// Layout notes:
//  - 8 lanes per query, 8 dims per lane (two float4 loads = 32B/lane/row;
//    an 8-lane group covers one 256B row fully coalesced).
//  - Head-pinned XCD swizzle: blockIdx % 32 selects (b,h); round-robin
//    dispatch (block i -> XCD i%8) then pins head bh to XCD bh%8, so each
//    XCD's 4MiB L2 holds exactly 4 heads' K+V (4 x 1MB) -> long-range delta
//    reads (517/1029 rows away) stay L2-resident instead of re-fetching HBM.

static constexpr int Bn = 4, Ln = 2048, Hn = 8, En = 64;
static constexpr int NDELTA = 17;

__global__ __launch_bounds__(256) void logsparse_attn_kernel(
    const float* __restrict__ Q,
    const float* __restrict__ K,
    const float* __restrict__ V,
    float* __restrict__ O)
{
    constexpr int deltas[NDELTA] = {0,1,2,3,4,5,6,7,9,13,21,37,69,133,261,517,1029};

    // Block swizzle: 2048 blocks = 32 heads x 64 query-chunks.
    // blockIdx = l*32 + bh  =>  bh = blockIdx%32 (so blockIdx%8 == bh%8).
    const int bh = blockIdx.x & 31;       // head id [0,32)
    const int l  = blockIdx.x >> 5;       // query-chunk [0,64), 32 queries each
    const int b  = bh >> 3;
    const int h  = bh & 7;

    const int sub = threadIdx.x & 7;      // 8 lanes per query, 8 dims each
    const int q   = l * 32 + (threadIdx.x >> 3);

    // row j of head (b,h) starts at ((b*Ln + j)*Hn + h)*En
    const size_t bhBase = ((size_t)b * Ln * Hn + (size_t)h) * (size_t)En;
    const size_t rowQ   = bhBase + (size_t)q * (Hn * En);
    const int    dimOff = sub * 8;

    // ---- load Q chunk (8 floats), fold scale = 1/sqrt(64) = 0.125 ----
    const float4 q0 = *(const float4*)(Q + rowQ + dimOff);
    const float4 q1 = *(const float4*)(Q + rowQ + dimOff + 4);
    float qf[8] = { q0.x*0.125f, q0.y*0.125f, q0.z*0.125f, q0.w*0.125f,
                    q1.x*0.125f, q1.y*0.125f, q1.z*0.125f, q1.w*0.125f };

    // ---- 17 sparse dot products ----
    float sc[NDELTA];
    #pragma unroll
    for (int d = 0; d < NDELTA; ++d) {
        const int j  = q - deltas[d];
        const int jc = (j < 0) ? 0 : j;
        const float* kp = K + bhBase + (size_t)jc * (Hn * En) + dimOff;
        const float4 k0 = *(const float4*)(kp);
        const float4 k1 = *(const float4*)(kp + 4);
        float s = qf[0]*k0.x + qf[1]*k0.y + qf[2]*k0.z + qf[3]*k0.w
                + qf[4]*k1.x + qf[5]*k1.y + qf[6]*k1.z + qf[7]*k1.w;
        // butterfly reduce across the 8-lane group (all lanes get the sum)
        s += __shfl_xor(s, 1);
        s += __shfl_xor(s, 2);
        s += __shfl_xor(s, 4);
        sc[d] = (j < 0) ? -__builtin_inff() : s;
    }

    // ---- softmax over the 17 scores (delta=0 always valid -> finite max) ----
    float m = sc[0];
    #pragma unroll
    for (int d = 1; d < NDELTA; ++d) m = fmaxf(m, sc[d]);
    float p[NDELTA];
    float sum = 0.0f;
    #pragma unroll
    for (int d = 0; d < NDELTA; ++d) {
        p[d] = __expf(sc[d] - m);   // exp(-inf) = 0 for masked-out (j<0)
        sum += p[d];
    }
    const float inv = 1.0f / sum;

    // ---- weighted sum of V rows (normalize at store) ----
    float acc[8] = {0,0,0,0,0,0,0,0};
    #pragma unroll
    for (int d = 0; d < NDELTA; ++d) {
        const int j  = q - deltas[d];
        const int jc = (j < 0) ? 0 : j;     // p[d]==0 when j<0, so clamp is safe
        const float* vp = V + bhBase + (size_t)jc * (Hn * En) + dimOff;
        const float4 v0 = *(const float4*)(vp);
        const float4 v1 = *(const float4*)(vp + 4);
        const float w = p[d];
        acc[0] = fmaf(w, v0.x, acc[0]);
        acc[1] = fmaf(w, v0.y, acc[1]);
        acc[2] = fmaf(w, v0.z, acc[2]);
        acc[3] = fmaf(w, v0.w, acc[3]);
        acc[4] = fmaf(w, v1.x, acc[4]);
        acc[5] = fmaf(w, v1.y, acc[5]);
        acc[6] = fmaf(w, v1.z, acc[6]);
        acc[7] = fmaf(w, v1.w, acc[7]);
    }

    float4 o0, o1;
    o0.x = acc[0]*inv; o0.y = acc[1]*inv; o0.z = acc[2]*inv; o0.w = acc[3]*inv;
    o1.x = acc[4]*inv; o1.y = acc[5]*inv; o1.z = acc[6]*inv; o1.w = acc[7]*inv;
    *(float4*)(O + rowQ + dimOff)     = o0;
    *(float4*)(O + rowQ + dimOff + 4) = o1;
}

extern "C" void kernel_launch(void* const* d_in, const int* in_sizes, int n_in,
                              void* d_out, int out_size, void* d_ws, size_t ws_size,
                              hipStream_t stream) {
    const float* Q = (const float*)d_in[0];
    const float* K = (const float*)d_in[1];
    const float* V = (const float*)d_in[2];
    float* O = (float*)d_out;

    const int total_threads = Bn * Hn * Ln * 8;   // 8 lanes per query
    logsparse_attn_kernel<<<total_threads / 256, 256, 0, stream>>>(Q, K, V, O);
}

// Round 4
// 102.097 us; speedup vs baseline: 1.0547x; 1.0547x over previous
//
#include <hip/hip_runtime.h>
#include <stdint.h>

// Log-sparse causal attention, B=4 L=2048 H=8 E=D=64, fp32 in/out.
// Allowed distances delta = q - j: {0..7, 9, 13, 21, 37, 69, 133, 261, 517, 1029}
// -> 17 candidate keys per query; sparse gather, no score matrix.
//
// R4: LDS staging of the near-delta span. A block owns 32 consecutive queries
// of one head; deltas <= 37 only touch rows [q0-37, q0+31] (69 rows). Stage
// K+V for that span in LDS once (2 x 69 x 68 floats = 37.5 KB -> 4 blocks/CU),
// serve 12/17 deltas from LDS; far deltas {69,133,261,517,1029} stay direct
// global loads. Cuts global row-reads per block 1088 -> 458.
// Row padded to 68 floats (272 B, 16B-aligned for ds_read_b128; rid*4+s*8 mod 32
// spreads bank accesses evenly -> balanced 8-cycle b128, no hot bank).

static constexpr int Bn = 4, Ln = 2048, Hn = 8, En = 64;
static constexpr int NDELTA = 17;
static constexpr int NEAR_MAX = 37;      // deltas <= this are staged
static constexpr int SPAN = 69;          // rows q0-37 .. q0+31
static constexpr int PADF = 68;          // floats per LDS row

__global__ __launch_bounds__(256) void logsparse_attn_kernel(
    const float* __restrict__ Q,
    const float* __restrict__ K,
    const float* __restrict__ V,
    float* __restrict__ O)
{
    constexpr int deltas[NDELTA] = {0,1,2,3,4,5,6,7,9,13,21,37,69,133,261,517,1029};

    __shared__ float Ks[SPAN * PADF];
    __shared__ float Vs[SPAN * PADF];

    // 2048 blocks = 32 heads x 64 query-chunks; bh = blockIdx%32 keeps one
    // head's blocks on one XCD under round-robin dispatch.
    const int bh = blockIdx.x & 31;
    const int l  = blockIdx.x >> 5;
    const int b  = bh >> 3;
    const int h  = bh & 7;
    const int q0 = l * 32;

    const int tid = threadIdx.x;
    const size_t bhBase = ((size_t)b * Ln * Hn + (size_t)h) * (size_t)En;
    constexpr int ROWF = Hn * En;        // 512 floats between consecutive rows

    // ---- cooperative staging: 69 rows x 16 float4-chunks, K then V ----
    for (int idx = tid; idx < 2 * SPAN * 16; idx += 256) {
        const int ten = (idx >= SPAN * 16);
        const int rem = ten ? idx - SPAN * 16 : idx;
        const int rid = rem >> 4;
        const int ch  = rem & 15;
        int g = q0 - NEAR_MAX + rid;
        if (g < 0) g = 0;                // finite data; masked later via p=0
        const float* src = (ten ? V : K) + bhBase + (size_t)g * ROWF + ch * 4;
        float* dst = (ten ? Vs : Ks) + rid * PADF + ch * 4;
        *(float4*)dst = *(const float4*)src;
    }
    __syncthreads();

    const int sub = tid & 7;             // 8 lanes per query, 8 dims each
    const int qq  = tid >> 3;            // query within block [0,32)
    const int q   = q0 + qq;
    const int dimOff = sub * 8;
    const size_t rowQ = bhBase + (size_t)q * ROWF;

    // ---- Q chunk (8 floats), fold scale = 1/sqrt(64) ----
    const float4 q0v = *(const float4*)(Q + rowQ + dimOff);
    const float4 q1v = *(const float4*)(Q + rowQ + dimOff + 4);
    const float qf[8] = { q0v.x*0.125f, q0v.y*0.125f, q0v.z*0.125f, q0v.w*0.125f,
                          q1v.x*0.125f, q1v.y*0.125f, q1v.z*0.125f, q1v.w*0.125f };

    // ---- 17 sparse dot products ----
    float sc[NDELTA];
    #pragma unroll
    for (int d = 0; d < NDELTA; ++d) {
        const int del = deltas[d];
        const int j   = q - del;
        float4 k0, k1;
        if (del <= NEAR_MAX) {           // compile-time branch under unroll
            const float* kp = Ks + (qq + NEAR_MAX - del) * PADF + dimOff;
            k0 = *(const float4*)(kp);
            k1 = *(const float4*)(kp + 4);
        } else {
            const int jc = (j < 0) ? 0 : j;
            const float* kp = K + bhBase + (size_t)jc * ROWF + dimOff;
            k0 = *(const float4*)(kp);
            k1 = *(const float4*)(kp + 4);
        }
        float s = qf[0]*k0.x + qf[1]*k0.y + qf[2]*k0.z + qf[3]*k0.w
                + qf[4]*k1.x + qf[5]*k1.y + qf[6]*k1.z + qf[7]*k1.w;
        s += __shfl_xor(s, 1);
        s += __shfl_xor(s, 2);
        s += __shfl_xor(s, 4);
        sc[d] = (j < 0) ? -__builtin_inff() : s;
    }

    // ---- softmax over 17 scores (delta=0 always valid -> finite max) ----
    float m = sc[0];
    #pragma unroll
    for (int d = 1; d < NDELTA; ++d) m = fmaxf(m, sc[d]);
    float p[NDELTA];
    float sum = 0.0f;
    #pragma unroll
    for (int d = 0; d < NDELTA; ++d) {
        p[d] = __expf(sc[d] - m);        // exp(-inf)=0 for masked
        sum += p[d];
    }
    const float inv = 1.0f / sum;

    // ---- weighted sum of V rows ----
    float acc[8] = {0,0,0,0,0,0,0,0};
    #pragma unroll
    for (int d = 0; d < NDELTA; ++d) {
        const int del = deltas[d];
        const int j   = q - del;
        float4 v0, v1;
        if (del <= NEAR_MAX) {
            const float* vp = Vs + (qq + NEAR_MAX - del) * PADF + dimOff;
            v0 = *(const float4*)(vp);
            v1 = *(const float4*)(vp + 4);
        } else {
            const int jc = (j < 0) ? 0 : j;   // p[d]==0 when j<0
            const float* vp = V + bhBase + (size_t)jc * ROWF + dimOff;
            v0 = *(const float4*)(vp);
            v1 = *(const float4*)(vp + 4);
        }
        const float w = p[d];
        acc[0] = fmaf(w, v0.x, acc[0]);
        acc[1] = fmaf(w, v0.y, acc[1]);
        acc[2] = fmaf(w, v0.z, acc[2]);
        acc[3] = fmaf(w, v0.w, acc[3]);
        acc[4] = fmaf(w, v1.x, acc[4]);
        acc[5] = fmaf(w, v1.y, acc[5]);
        acc[6] = fmaf(w, v1.z, acc[6]);
        acc[7] = fmaf(w, v1.w, acc[7]);
    }

    float4 o0, o1;
    o0.x = acc[0]*inv; o0.y = acc[1]*inv; o0.z = acc[2]*inv; o0.w = acc[3]*inv;
    o1.x = acc[4]*inv; o1.y = acc[5]*inv; o1.z = acc[6]*inv; o1.w = acc[7]*inv;
    *(float4*)(O + rowQ + dimOff)     = o0;
    *(float4*)(O + rowQ + dimOff + 4) = o1;
}

extern "C" void kernel_launch(void* const* d_in, const int* in_sizes, int n_in,
                              void* d_out, int out_size, void* d_ws, size_t ws_size,
                              hipStream_t stream) {
    const float* Q = (const float*)d_in[0];
    const float* K = (const float*)d_in[1];
    const float* V = (const float*)d_in[2];
    float* O = (float*)d_out;

    const int nblocks = Bn * Hn * (Ln / 32);   // 2048 blocks, 32 queries each
    logsparse_attn_kernel<<<nblocks, 256, 0, stream>>>(Q, K, V, O);
}